// Round 9
// baseline (1346.504 us; speedup 1.0000x reference)
//
#include <hip/hip_runtime.h>

#define NN 16000   // nodes
#define NE 64000   // edges
#define HD 90      // hidden
#define NG 512     // graphs

typedef float f32x4 __attribute__((ext_vector_type(4)));
typedef short s16x8 __attribute__((ext_vector_type(8)));

// round-half-up f32 -> bf16
__device__ __forceinline__ unsigned short rhu1(float f) {
  return (unsigned short)((__builtin_bit_cast(unsigned int, f) + 0x8000u) >> 16);
}
// pack two f32 -> bf16x2 (lo in low half), RHU rounding
__device__ __forceinline__ unsigned int rhu_pack(float lo, float hi) {
  unsigned int ul = __builtin_bit_cast(unsigned int, lo) + 0x8000u;
  unsigned int uh = __builtin_bit_cast(unsigned int, hi) + 0x8000u;
  return __builtin_amdgcn_perm(uh, ul, 0x07060302u);
}
__device__ __forceinline__ float bfhi(unsigned int u) {
  return __builtin_bit_cast(float, u & 0xFFFF0000u);
}
__device__ __forceinline__ float bflo(unsigned int u) {
  return __builtin_bit_cast(float, u << 16);
}

// h0 = concat(x, pos) : [NN, 16]
__global__ void concat_kernel(const float* __restrict__ x, const float* __restrict__ pos,
                              float* __restrict__ h0) {
  int idx = blockIdx.x * 256 + threadIdx.x;
  if (idx >= NN * 16) return;
  int n = idx >> 4, c = idx & 15;
  h0[idx] = (c < 13) ? x[n * 13 + c] : pos[n * 3 + (c - 13)];
}

// he_bf[e][k] : [NE, 96] bf16. k<90: relu(edge MLP); k==90: 1.0 (bias row); k>90: 0
__global__ void edge_mlp_bf(const float* __restrict__ ea, const float* __restrict__ w1,
                            const float* __restrict__ b1, unsigned short* __restrict__ he) {
  int idx = blockIdx.x * 256 + threadIdx.x;
  if (idx >= NE * 96) return;
  int e = idx / 96, k = idx - e * 96;
  unsigned short v;
  if (k < 90) {
    const float* a = ea + e * 8;
    float acc = b1[k];
#pragma unroll
    for (int j = 0; j < 8; j++) acc = fmaf(a[j], w1[j * HD + k], acc);
    v = rhu1(fmaxf(acc, 0.f));
  } else {
    v = (k == 90) ? (unsigned short)0x3F80 : (unsigned short)0;  // bf16(1.0) / 0
  }
  he[idx] = v;
}

// W' prep in MFMA-B-fragment order: shorts laid out as
//   [i][tile t(NTT)][chunk c(3)][lane(64)][j(8)]
// value(i,t,c,lane,j): hk=c*32+(lane>>4)*8+j, o=t*16+(lane&15);
//   hk<90 -> w2[hk][i*OC+o]; hk==90 -> b2[i*OC+o]; else 0.   One block per (i,c).
template <int OC, int NTT>
__global__ void wprep_frag(const float* __restrict__ w2, const float* __restrict__ b2,
                           unsigned short* __restrict__ wout, int inc_oc) {
  const int i = blockIdx.x / 3, c = blockIdx.x - 3 * (blockIdx.x / 3);
  __shared__ float t_s[32 * 100];
  const int tid = threadIdx.x;
  for (int idx = tid; idx < 32 * 96; idx += 256) {
    int kk = idx / 96, o = idx - kk * 96;
    int hk = c * 32 + kk;
    float v = 0.f;
    if (o < OC) {
      if (hk < 90) v = w2[hk * inc_oc + i * OC + o];        // coalesced along o
      else if (hk == 90) v = b2[i * OC + o];
    }
    t_s[kk * 100 + o] = v;
  }
  __syncthreads();
  unsigned int* wo = (unsigned int*)(wout + (size_t)i * NTT * 3 * 512) + c * 256;
  for (int idx = tid; idx < NTT * 256; idx += 256) {
    int t = idx >> 8, r = idx & 255;
    int lane = r >> 2, u = r & 3;
    int kk = (lane >> 4) * 8 + 2 * u;
    int o = t * 16 + (lane & 15);
    wo[(size_t)t * 3 * 256 + lane * 4 + u] = rhu_pack(t_s[kk * 100 + o], t_s[(kk + 1) * 100 + o]);
  }
}

// Fused message GEMM + scatter, i-outer, barrier-free K-loop, rolling W prefetch.
//   tmp_i[e][o] = sum_hk he[e][hk] * W'[i][hk][o]   (3 chained MFMAs; he in regs)
//   acc[e][o]  += z[e][i] * tmp_i[e][o]             (f32 fma; z bf16 from LDS)
// WM=4: each wave = 4 m-tiles (64 edges) x 3 n-tiles — same 9 W' fragments
// amortized over 2x edges vs round 8 (halves per-CU L1 traffic, the round-8 bound).
// launch_bounds(...,3): no forced spill (round-6 lesson); natural occ ~12 waves/CU.
template <int ILIM, int OC, int NTT, int NWG, int EPB, int BLK>
__global__ __launch_bounds__(BLK, 3)
void msg_mfma(const unsigned short* __restrict__ he,
              const float* __restrict__ nin,
              const int* __restrict__ src, const int* __restrict__ dst,
              const unsigned short* __restrict__ wp,
              float* __restrict__ agg) {
  constexpr int WMB = EPB / 64;            // m-wave-groups (64 edges each)
  constexpr int TPE = BLK / EPB;
  __shared__ unsigned short zb[ILIM * WMB * 64];   // [i][wm][q][mt][r] bf16
  __shared__ int dst_s[EPB];
  const int tid = threadIdx.x;
  const int e0 = blockIdx.x * EPB;
  const int wid = tid >> 6, l = tid & 63, ln = tid & 15, q = (tid & 63) >> 4;
  const int wn = wid % NWG, wm = wid / NWG;
  const int eb = wm * 64;
  const int wn3 = wn * 3;

  if (tid < EPB) dst_s[tid] = dst[e0 + tid];

  // stage z (bf16), layout so each wave reads 2x b128 broadcast per i:
  //   e -> wm_e=e>>6, mt=(e>>4)&3, q_e=(e>>2)&3, r=e&3
  //   slot(e,i) = ((i*WMB + wm_e)*4 + q_e)*16 + mt*4 + r
  {
    const int e = tid % EPB, jj = tid / EPB;
    const int base = ((e >> 6) * 4 + ((e >> 2) & 3)) * 16 + ((e >> 4) & 3) * 4 + (e & 3);
    const float* zr = nin + (size_t)src[e0 + e] * ILIM;
    for (int p = jj; p < ILIM / 2; p += TPE) {
      const float2 v = *(const float2*)(zr + 2 * p);
      zb[(2 * p) * (WMB * 64) + base] = rhu1(v.x);
      zb[(2 * p + 1) * (WMB * 64) + base] = rhu1(v.y);
    }
  }

  // A-fragments: raw bf16 he, register-resident for the whole kernel
  s16x8 af[4][3];
#pragma unroll
  for (int mt = 0; mt < 4; mt++) {
    const unsigned short* hr = he + (size_t)(e0 + eb + mt * 16 + ln) * 96 + q * 8;
#pragma unroll
    for (int c = 0; c < 3; c++) af[mt][c] = *(const s16x8*)(hr + c * 32);
  }

  // W' fragment slots (single buffer, rolling reload); frag (i,T,c) at
  // shorts offset ((i*NTT + T)*3 + c)*512, T = wn3+ntl
  const unsigned short* wl = wp + l * 8;
  uint4 ba[9];
#pragma unroll
  for (int ntl = 0; ntl < 3; ntl++) {
    const unsigned short* wg = wl + (size_t)(wn3 + ntl) * 3 * 512;
#pragma unroll
    for (int c = 0; c < 3; c++) ba[ntl * 3 + c] = *(const uint4*)(wg + c * 512);
  }

  __syncthreads();   // zb/dst_s ready; no barriers after this

  f32x4 acc[4][3];
#pragma unroll
  for (int mt = 0; mt < 4; mt++)
#pragma unroll
    for (int nt = 0; nt < 3; nt++) acc[mt][nt] = (f32x4)0.f;

#pragma clang loop unroll(disable)
  for (int i = 0; i < ILIM; i++) {
    // z for this i: two b128 broadcast reads -> 16 bf16 (4 rows x 4 m-tiles)
    const int zoff = ((i * WMB + wm) * 4 + q) * 16;
    const uint4 zu0 = *(const uint4*)&zb[zoff];
    const uint4 zu1 = *(const uint4*)&zb[zoff + 8];
    f32x4 zv[4];
    zv[0][0] = bflo(zu0.x); zv[0][1] = bfhi(zu0.x); zv[0][2] = bflo(zu0.y); zv[0][3] = bfhi(zu0.y);
    zv[1][0] = bflo(zu0.z); zv[1][1] = bfhi(zu0.z); zv[1][2] = bflo(zu0.w); zv[1][3] = bfhi(zu0.w);
    zv[2][0] = bflo(zu1.x); zv[2][1] = bfhi(zu1.x); zv[2][2] = bflo(zu1.y); zv[2][3] = bfhi(zu1.y);
    zv[3][0] = bflo(zu1.z); zv[3][1] = bfhi(zu1.z); zv[3][2] = bflo(zu1.w); zv[3][3] = bfhi(zu1.w);
#pragma unroll
    for (int ntl = 0; ntl < 3; ntl++) {
      const s16x8 wb0 = __builtin_bit_cast(s16x8, ba[ntl * 3 + 0]);
      const s16x8 wb1 = __builtin_bit_cast(s16x8, ba[ntl * 3 + 1]);
      const s16x8 wb2 = __builtin_bit_cast(s16x8, ba[ntl * 3 + 2]);
#pragma unroll
      for (int mt = 0; mt < 4; mt++) {
        f32x4 t = __builtin_amdgcn_mfma_f32_16x16x32_bf16(af[mt][0], wb0, (f32x4)0.f, 0, 0, 0);
        t = __builtin_amdgcn_mfma_f32_16x16x32_bf16(af[mt][1], wb1, t, 0, 0, 0);
        t = __builtin_amdgcn_mfma_f32_16x16x32_bf16(af[mt][2], wb2, t, 0, 0, 0);
        acc[mt][ntl] += zv[mt] * t;
      }
      // rolling reload of this tile's 3 slots for i+1 (consumed next iter)
      if (i + 1 < ILIM) {
        const unsigned short* wg = wl + ((size_t)(i + 1) * NTT + wn3 + ntl) * 3 * 512;
        ba[ntl * 3 + 0] = *(const uint4*)(wg);
        ba[ntl * 3 + 1] = *(const uint4*)(wg + 512);
        ba[ntl * 3 + 2] = *(const uint4*)(wg + 1024);
      }
    }
  }

  // epilogue: D[row=q*4+r][col=ln] -> atomicAdd agg[dst]
#pragma unroll
  for (int mt = 0; mt < 4; mt++) {
#pragma unroll
    for (int ntl = 0; ntl < 3; ntl++) {
      int o = wn * 48 + ntl * 16 + ln;
      if (o < OC) {
#pragma unroll
        for (int r = 0; r < 4; r++) {
          int el = eb + mt * 16 + q * 4 + r;
          atomicAdd(agg + (size_t)dst_s[el] * OC + o, acc[mt][ntl][r]);
        }
      }
    }
  }
}

// out[n][o] = relu(agg[n][o] + sum_i nin[n][i]*root[i][o] + bias[o])   (fp32 exact)
template <int IN_C, int OC>
__global__ void node_kernel(const float* __restrict__ agg, const float* __restrict__ nin,
                            const float* __restrict__ root, const float* __restrict__ bias,
                            float* __restrict__ out) {
  int idx = blockIdx.x * 256 + threadIdx.x;
  if (idx >= NN * OC) return;
  int n = idx / OC, o = idx - n * OC;
  float acc = agg[idx] + bias[o];
  const float* inp = nin + (size_t)n * IN_C;
#pragma unroll 6
  for (int i = 0; i < IN_C; i++) acc = fmaf(inp[i], root[i * OC + o], acc);
  out[idx] = fmaxf(acc, 0.f);
}

// per-graph: pool (batch sorted -> binary search) + fc1 + out
__global__ void pool_mlp_kernel(const float* __restrict__ h3, const int* __restrict__ batch,
                                const float* __restrict__ fc1_w, const float* __restrict__ fc1_b,
                                const float* __restrict__ out_w, const float* __restrict__ out_b,
                                float* __restrict__ out) {
  const int b = blockIdx.x;
  const int tid = threadIdx.x;
  __shared__ float g[45];
  __shared__ float go[90];
  __shared__ int rng[2];
  if (tid < 2) {
    int target = b + tid;
    int lo = 0, hi = NN;
    while (lo < hi) { int mid = (lo + hi) >> 1; if (batch[mid] < target) lo = mid + 1; else hi = mid; }
    rng[tid] = lo;
  }
  __syncthreads();
  const int s = rng[0], e = rng[1];
  if (tid < 45) {
    float acc = 0.f;
    for (int n = s; n < e; n++) acc += h3[n * 45 + tid];
    g[tid] = acc;
  }
  __syncthreads();
  if (tid < 90) {
    float acc = fc1_b[tid];
#pragma unroll 5
    for (int i = 0; i < 45; i++) acc = fmaf(g[i], fc1_w[i * 90 + tid], acc);
    go[tid] = fmaxf(acc, 0.f) * out_w[tid];
  }
  __syncthreads();
  if (tid == 0) {
    float acc = out_b[0];
    for (int i = 0; i < 90; i++) acc += go[i];
    out[b] = acc;
  }
}

extern "C" void kernel_launch(void* const* d_in, const int* in_sizes, int n_in,
                              void* d_out, int out_size, void* d_ws, size_t ws_size,
                              hipStream_t stream) {
  const float* x       = (const float*)d_in[0];
  const float* pos     = (const float*)d_in[1];
  const float* ea      = (const float*)d_in[2];
  const int*   eidx    = (const int*)d_in[3];
  const int*   batch   = (const int*)d_in[4];
  const float* c1_w1   = (const float*)d_in[5];
  const float* c1_b1   = (const float*)d_in[6];
  const float* c1_w2   = (const float*)d_in[7];
  const float* c1_b2   = (const float*)d_in[8];
  const float* c1_root = (const float*)d_in[9];
  const float* c1_bias = (const float*)d_in[10];
  const float* c2_w1   = (const float*)d_in[11];
  const float* c2_b1   = (const float*)d_in[12];
  const float* c2_w2   = (const float*)d_in[13];
  const float* c2_b2   = (const float*)d_in[14];
  const float* c2_root = (const float*)d_in[15];
  const float* c2_bias = (const float*)d_in[16];
  const float* c3_w1   = (const float*)d_in[17];
  const float* c3_b1   = (const float*)d_in[18];
  const float* c3_w2   = (const float*)d_in[19];
  const float* c3_b2   = (const float*)d_in[20];
  const float* c3_root = (const float*)d_in[21];
  const float* c3_bias = (const float*)d_in[22];
  const float* fc1_w   = (const float*)d_in[23];
  const float* fc1_b   = (const float*)d_in[24];
  const float* out_w   = (const float*)d_in[25];
  const float* out_b   = (const float*)d_in[26];
  const int* src = eidx;
  const int* dst = eidx + NE;

  // workspace carve
  float* ws  = (float*)d_ws;
  float* h0  = ws;                       // NN*16
  float* h1  = h0 + NN * 16;             // NN*90
  float* h2  = h1 + NN * 90;             // NN*90
  float* h3  = h2 + NN * 90;             // NN*45
  float* agg = h3 + NN * 45;             // NN*90
  unsigned short* he_bf = (unsigned short*)(agg + NN * 90);   // NE*96
  unsigned short* wp1 = he_bf + (size_t)NE * 96;              // 16*6*3*512
  unsigned short* wp2 = wp1 + (size_t)16 * 6 * 3 * 512;       // 90*6*3*512
  unsigned short* wp3 = wp2 + (size_t)90 * 6 * 3 * 512;       // 90*3*3*512

  concat_kernel<<<(NN * 16) / 256, 256, 0, stream>>>(x, pos, h0);

  wprep_frag<90, 6><<<16 * 3, 256, 0, stream>>>(c1_w2, c1_b2, wp1, 16 * 90);
  wprep_frag<90, 6><<<90 * 3, 256, 0, stream>>>(c2_w2, c2_b2, wp2, 90 * 90);
  wprep_frag<45, 3><<<90 * 3, 256, 0, stream>>>(c3_w2, c3_b2, wp3, 90 * 45);

  // conv1: 16 -> 90   (128 edges/block, 4 waves: 2 m-groups x 2 n-groups, WM=4)
  hipMemsetAsync(agg, 0, (size_t)NN * 90 * sizeof(float), stream);
  edge_mlp_bf<<<(NE * 96) / 256, 256, 0, stream>>>(ea, c1_w1, c1_b1, he_bf);
  msg_mfma<16, 90, 6, 2, 128, 256><<<NE / 128, 256, 0, stream>>>(he_bf, h0, src, dst, wp1, agg);
  node_kernel<16, 90><<<(NN * 90) / 256, 256, 0, stream>>>(agg, h0, c1_root, c1_bias, h1);

  // conv2: 90 -> 90
  hipMemsetAsync(agg, 0, (size_t)NN * 90 * sizeof(float), stream);
  edge_mlp_bf<<<(NE * 96) / 256, 256, 0, stream>>>(ea, c2_w1, c2_b1, he_bf);
  msg_mfma<90, 90, 6, 2, 128, 256><<<NE / 128, 256, 0, stream>>>(he_bf, h1, src, dst, wp2, agg);
  node_kernel<90, 90><<<(NN * 90) / 256, 256, 0, stream>>>(agg, h1, c2_root, c2_bias, h2);

  // conv3: 90 -> 45   (256 edges/block, 4 waves: 4 m-groups x 1 n-group, WM=4)
  hipMemsetAsync(agg, 0, (size_t)NN * 45 * sizeof(float), stream);
  edge_mlp_bf<<<(NE * 96) / 256, 256, 0, stream>>>(ea, c3_w1, c3_b1, he_bf);
  msg_mfma<90, 45, 3, 1, 256, 256><<<NE / 256, 256, 0, stream>>>(he_bf, h2, src, dst, wp3, agg);
  node_kernel<90, 45><<<(NN * 45 + 255) / 256, 256, 0, stream>>>(agg, h2, c3_root, c3_bias, h3);

  pool_mlp_kernel<<<NG, 128, 0, stream>>>(h3, batch, fc1_w, fc1_b, out_w, out_b, (float*)d_out);
}

// Round 10
// 610.563 us; speedup vs baseline: 2.2053x; 2.2053x over previous
//
#include <hip/hip_runtime.h>

#define NN 16000   // nodes
#define NE 64000   // edges
#define HD 90      // hidden
#define NG 512     // graphs

typedef float f32x4 __attribute__((ext_vector_type(4)));
typedef float f32x16 __attribute__((ext_vector_type(16)));
typedef short s16x8 __attribute__((ext_vector_type(8)));

// round-half-up f32 -> bf16
__device__ __forceinline__ unsigned short rhu1(float f) {
  return (unsigned short)((__builtin_bit_cast(unsigned int, f) + 0x8000u) >> 16);
}
// pack two f32 -> bf16x2 (lo in low half), RHU rounding
__device__ __forceinline__ unsigned int rhu_pack(float lo, float hi) {
  unsigned int ul = __builtin_bit_cast(unsigned int, lo) + 0x8000u;
  unsigned int uh = __builtin_bit_cast(unsigned int, hi) + 0x8000u;
  return __builtin_amdgcn_perm(uh, ul, 0x07060302u);
}

// h0 = concat(x, pos) : [NN, 16]
__global__ void concat_kernel(const float* __restrict__ x, const float* __restrict__ pos,
                              float* __restrict__ h0) {
  int idx = blockIdx.x * 256 + threadIdx.x;
  if (idx >= NN * 16) return;
  int n = idx >> 4, c = idx & 15;
  h0[idx] = (c < 13) ? x[n * 13 + c] : pos[n * 3 + (c - 13)];
}

// he_bf[e][k] : [NE, 96] bf16. k<90: relu(edge MLP); k==90: 1.0 (bias row); k>90: 0
__global__ void edge_mlp_bf(const float* __restrict__ ea, const float* __restrict__ w1,
                            const float* __restrict__ b1, unsigned short* __restrict__ he) {
  int idx = blockIdx.x * 256 + threadIdx.x;
  if (idx >= NE * 96) return;
  int e = idx / 96, k = idx - e * 96;
  unsigned short v;
  if (k < 90) {
    const float* a = ea + e * 8;
    float acc = b1[k];
#pragma unroll
    for (int j = 0; j < 8; j++) acc = fmaf(a[j], w1[j * HD + k], acc);
    v = rhu1(fmaxf(acc, 0.f));
  } else {
    v = (k == 90) ? (unsigned short)0x3F80 : (unsigned short)0;  // bf16(1.0) / 0
  }
  he[idx] = v;
}

// W' prep, 32x32x16 B-fragment order: shorts as [i][ot(NOT)][c(6)][lane(64)][j(8)]
//   o = ot*32 + (lane&31), hk = c*16 + (lane>>5)*8 + j
//   hk<90 -> w2[hk][i*OC+o]; hk==90 -> b2[i*OC+o]; else 0.  One block per i.
template <int OC, int NOT>
__global__ void wprep_frag32(const float* __restrict__ w2, const float* __restrict__ b2,
                             unsigned short* __restrict__ wout, int inc_oc) {
  const int i = blockIdx.x;
  unsigned int* wo = (unsigned int*)(wout + (size_t)i * NOT * 6 * 512);
  for (int u = threadIdx.x; u < NOT * 6 * 256; u += 256) {
    int f = u >> 8, r = u & 255;
    int ot = f / 6, c = f - 6 * ot;
    int lane = r >> 2, uu = r & 3;
    int o = ot * 32 + (lane & 31);
    int hk = c * 16 + ((lane >> 5) << 3) + 2 * uu;
    float v0 = 0.f, v1 = 0.f;
    if (o < OC) {
      if (hk < 90) v0 = w2[hk * inc_oc + i * OC + o];
      else if (hk == 90) v0 = b2[i * OC + o];
      int hk1 = hk + 1;
      if (hk1 < 90) v1 = w2[hk1 * inc_oc + i * OC + o];
      else if (hk1 == 90) v1 = b2[i * OC + o];
    }
    wo[u] = rhu_pack(v0, v1);
  }
}

// Fused message GEMM + scatter, i-outer, barrier-free K-loop, 32x32x16 MFMA core:
//   tmp_i[e][o] = sum_hk he[e][hk] * W'[i][hk][o]   (6 chained 32x32x16 MFMAs)
//   acc[e][o]  += z[e][i] * tmp_i[e][o]             (f32 fma; z f32 from LDS)
// Wave tile: 2 m-tiles (64 edges) x 1 n-tile (32 out). 6 B-frags (24 VGPR)
// rolling-reloaded; af 48 VGPR resident; acc 32 in AGPR. Arch demand ~116 —
// inside the proven-safe envelope (R5/R9: ~130+ collapses the allocator).
// Block: MWG m-wave-groups x NWG n-wave-groups; EPB = MWG*64 edges.
template <int ILIM, int OC, int NWG, int MWG, int BLK>
__global__ __launch_bounds__(BLK, 3)
void msg_mfma(const unsigned short* __restrict__ he,
              const float* __restrict__ nin,
              const int* __restrict__ src, const int* __restrict__ dst,
              const unsigned short* __restrict__ wp,
              float* __restrict__ agg) {
  constexpr int EPB = MWG * 64;
  constexpr int MT = EPB / 32;             // absolute 32-edge m-tiles per block
  constexpr int TPE = BLK / EPB;
  __shared__ float zb[ILIM * MT * 32];     // [i][mta][rq][h][4] f32
  __shared__ int dst_s[EPB];
  const int tid = threadIdx.x;
  const int e0 = blockIdx.x * EPB;
  const int wid = tid >> 6, l = tid & 63, ln32 = tid & 31, h = (tid & 63) >> 5;
  const int wn = wid % NWG, wm = wid / NWG;

  if (tid < EPB) dst_s[tid] = dst[e0 + tid];

  // stage z (f32): e -> mta=e>>5, row=e&31 -> rq=row>>3, hh=(row>>2)&1, rr=row&3
  //   slot(e,i) = ((i*MT + mta)*4 + rq)*8 + hh*4 + rr
  {
    const int e = tid % EPB, jj = tid / EPB;
    const int row = e & 31;
    const int base = ((e >> 5) * 4 + (row >> 3)) * 8 + ((row >> 2) & 1) * 4 + (row & 3);
    const float* zr = nin + (size_t)src[e0 + e] * ILIM;
    for (int p = jj; p < ILIM / 2; p += TPE) {
      const float2 v = *(const float2*)(zr + 2 * p);
      zb[(2 * p) * (MT * 32) + base] = v.x;
      zb[(2 * p + 1) * (MT * 32) + base] = v.y;
    }
  }

  // A-fragments: he rows, 32x32x16 A layout (m=lane&31, k=c*16+(lane>>5)*8+j)
  s16x8 af[2][6];
#pragma unroll
  for (int mt = 0; mt < 2; mt++) {
    const unsigned short* hr = he + (size_t)(e0 + wm * 64 + mt * 32 + ln32) * 96 + h * 8;
#pragma unroll
    for (int c = 0; c < 6; c++) af[mt][c] = *(const s16x8*)(hr + c * 16);
  }

  // B-fragment slots (single buffer, rolling reload); frag (i,ot,c) at
  // shorts offset ((i*NWG... actually ((i*NOT + ot)*6 + c)*512, NOT==NWG here
  const unsigned short* wl = wp + l * 8;
  s16x8 bf[6];
#pragma unroll
  for (int c = 0; c < 6; c++)
    bf[c] = *(const s16x8*)(wl + ((size_t)wn * 6 + c) * 512);

  __syncthreads();   // zb/dst_s ready; no barriers after this

  f32x16 acc[2];
  acc[0] = (f32x16)0.f;
  acc[1] = (f32x16)0.f;

#pragma clang loop unroll(disable)
  for (int i = 0; i < ILIM; i++) {
#pragma unroll
    for (int mt = 0; mt < 2; mt++) {
      const int mta = wm * 2 + mt;
      // zv: 4 b128 broadcast reads -> 16 f32 (rows (rq*8 + h*4 + rr))
      f32x16 zvv;
#pragma unroll
      for (int rq = 0; rq < 4; rq++) {
        const f32x4 zq = *(const f32x4*)&zb[((i * MT + mta) * 4 + rq) * 8 + h * 4];
        zvv[4 * rq + 0] = zq[0]; zvv[4 * rq + 1] = zq[1];
        zvv[4 * rq + 2] = zq[2]; zvv[4 * rq + 3] = zq[3];
      }
      f32x16 t = __builtin_amdgcn_mfma_f32_32x32x16_bf16(af[mt][0], bf[0], (f32x16)0.f, 0, 0, 0);
      t = __builtin_amdgcn_mfma_f32_32x32x16_bf16(af[mt][1], bf[1], t, 0, 0, 0);
      t = __builtin_amdgcn_mfma_f32_32x32x16_bf16(af[mt][2], bf[2], t, 0, 0, 0);
      t = __builtin_amdgcn_mfma_f32_32x32x16_bf16(af[mt][3], bf[3], t, 0, 0, 0);
      t = __builtin_amdgcn_mfma_f32_32x32x16_bf16(af[mt][4], bf[4], t, 0, 0, 0);
      t = __builtin_amdgcn_mfma_f32_32x32x16_bf16(af[mt][5], bf[5], t, 0, 0, 0);
      acc[mt] += zvv * t;
    }
    // rolling reload of this wave's 6 B-frags for i+1 (consumed next iter)
    if (i + 1 < ILIM) {
      const unsigned short* wg = wl + ((size_t)(i + 1) * NWG + wn) * 6 * 512;
#pragma unroll
      for (int c = 0; c < 6; c++) bf[c] = *(const s16x8*)(wg + c * 512);
    }
  }

  // epilogue: D[row=(r&3)+8*(r>>2)+4*h][col=ln32] -> atomicAdd agg[dst]
  const int o = wn * 32 + ln32;
  if (o < OC) {
#pragma unroll
    for (int mt = 0; mt < 2; mt++) {
#pragma unroll
      for (int r = 0; r < 16; r++) {
        int el = wm * 64 + mt * 32 + (r & 3) + 8 * (r >> 2) + 4 * h;
        atomicAdd(agg + (size_t)dst_s[el] * OC + o, acc[mt][r]);
      }
    }
  }
}

// out[n][o] = relu(agg[n][o] + sum_i nin[n][i]*root[i][o] + bias[o])   (fp32 exact)
template <int IN_C, int OC>
__global__ void node_kernel(const float* __restrict__ agg, const float* __restrict__ nin,
                            const float* __restrict__ root, const float* __restrict__ bias,
                            float* __restrict__ out) {
  int idx = blockIdx.x * 256 + threadIdx.x;
  if (idx >= NN * OC) return;
  int n = idx / OC, o = idx - n * OC;
  float acc = agg[idx] + bias[o];
  const float* inp = nin + (size_t)n * IN_C;
#pragma unroll 6
  for (int i = 0; i < IN_C; i++) acc = fmaf(inp[i], root[i * OC + o], acc);
  out[idx] = fmaxf(acc, 0.f);
}

// per-graph: pool (batch sorted -> binary search) + fc1 + out
__global__ void pool_mlp_kernel(const float* __restrict__ h3, const int* __restrict__ batch,
                                const float* __restrict__ fc1_w, const float* __restrict__ fc1_b,
                                const float* __restrict__ out_w, const float* __restrict__ out_b,
                                float* __restrict__ out) {
  const int b = blockIdx.x;
  const int tid = threadIdx.x;
  __shared__ float g[45];
  __shared__ float go[90];
  __shared__ int rng[2];
  if (tid < 2) {
    int target = b + tid;
    int lo = 0, hi = NN;
    while (lo < hi) { int mid = (lo + hi) >> 1; if (batch[mid] < target) lo = mid + 1; else hi = mid; }
    rng[tid] = lo;
  }
  __syncthreads();
  const int s = rng[0], e = rng[1];
  if (tid < 45) {
    float acc = 0.f;
    for (int n = s; n < e; n++) acc += h3[n * 45 + tid];
    g[tid] = acc;
  }
  __syncthreads();
  if (tid < 90) {
    float acc = fc1_b[tid];
#pragma unroll 5
    for (int i = 0; i < 45; i++) acc = fmaf(g[i], fc1_w[i * 90 + tid], acc);
    go[tid] = fmaxf(acc, 0.f) * out_w[tid];
  }
  __syncthreads();
  if (tid == 0) {
    float acc = out_b[0];
    for (int i = 0; i < 90; i++) acc += go[i];
    out[b] = acc;
  }
}

extern "C" void kernel_launch(void* const* d_in, const int* in_sizes, int n_in,
                              void* d_out, int out_size, void* d_ws, size_t ws_size,
                              hipStream_t stream) {
  const float* x       = (const float*)d_in[0];
  const float* pos     = (const float*)d_in[1];
  const float* ea      = (const float*)d_in[2];
  const int*   eidx    = (const int*)d_in[3];
  const int*   batch   = (const int*)d_in[4];
  const float* c1_w1   = (const float*)d_in[5];
  const float* c1_b1   = (const float*)d_in[6];
  const float* c1_w2   = (const float*)d_in[7];
  const float* c1_b2   = (const float*)d_in[8];
  const float* c1_root = (const float*)d_in[9];
  const float* c1_bias = (const float*)d_in[10];
  const float* c2_w1   = (const float*)d_in[11];
  const float* c2_b1   = (const float*)d_in[12];
  const float* c2_w2   = (const float*)d_in[13];
  const float* c2_b2   = (const float*)d_in[14];
  const float* c2_root = (const float*)d_in[15];
  const float* c2_bias = (const float*)d_in[16];
  const float* c3_w1   = (const float*)d_in[17];
  const float* c3_b1   = (const float*)d_in[18];
  const float* c3_w2   = (const float*)d_in[19];
  const float* c3_b2   = (const float*)d_in[20];
  const float* c3_root = (const float*)d_in[21];
  const float* c3_bias = (const float*)d_in[22];
  const float* fc1_w   = (const float*)d_in[23];
  const float* fc1_b   = (const float*)d_in[24];
  const float* out_w   = (const float*)d_in[25];
  const float* out_b   = (const float*)d_in[26];
  const int* src = eidx;
  const int* dst = eidx + NE;

  // workspace carve
  float* ws  = (float*)d_ws;
  float* h0  = ws;                       // NN*16
  float* h1  = h0 + NN * 16;             // NN*90
  float* h2  = h1 + NN * 90;             // NN*90
  float* h3  = h2 + NN * 90;             // NN*45
  float* agg = h3 + NN * 45;             // NN*90
  unsigned short* he_bf = (unsigned short*)(agg + NN * 90);   // NE*96
  unsigned short* wp1 = he_bf + (size_t)NE * 96;              // 16*3*6*512
  unsigned short* wp2 = wp1 + (size_t)16 * 3 * 6 * 512;       // 90*3*6*512
  unsigned short* wp3 = wp2 + (size_t)90 * 3 * 6 * 512;       // 90*2*6*512

  concat_kernel<<<(NN * 16) / 256, 256, 0, stream>>>(x, pos, h0);

  wprep_frag32<90, 3><<<16, 256, 0, stream>>>(c1_w2, c1_b2, wp1, 16 * 90);
  wprep_frag32<90, 3><<<90, 256, 0, stream>>>(c2_w2, c2_b2, wp2, 90 * 90);
  wprep_frag32<45, 2><<<90, 256, 0, stream>>>(c3_w2, c3_b2, wp3, 90 * 45);

  // conv1: 16 -> 90   (6-wave blocks: 2 m-groups x 3 n-groups, 128 edges)
  hipMemsetAsync(agg, 0, (size_t)NN * 90 * sizeof(float), stream);
  edge_mlp_bf<<<(NE * 96) / 256, 256, 0, stream>>>(ea, c1_w1, c1_b1, he_bf);
  msg_mfma<16, 90, 3, 2, 384><<<NE / 128, 384, 0, stream>>>(he_bf, h0, src, dst, wp1, agg);
  node_kernel<16, 90><<<(NN * 90) / 256, 256, 0, stream>>>(agg, h0, c1_root, c1_bias, h1);

  // conv2: 90 -> 90
  hipMemsetAsync(agg, 0, (size_t)NN * 90 * sizeof(float), stream);
  edge_mlp_bf<<<(NE * 96) / 256, 256, 0, stream>>>(ea, c2_w1, c2_b1, he_bf);
  msg_mfma<90, 90, 3, 2, 384><<<NE / 128, 384, 0, stream>>>(he_bf, h1, src, dst, wp2, agg);
  node_kernel<90, 90><<<(NN * 90) / 256, 256, 0, stream>>>(agg, h1, c2_root, c2_bias, h2);

  // conv3: 90 -> 45   (4-wave blocks: 2 m-groups x 2 n-groups, 128 edges)
  hipMemsetAsync(agg, 0, (size_t)NN * 45 * sizeof(float), stream);
  edge_mlp_bf<<<(NE * 96) / 256, 256, 0, stream>>>(ea, c3_w1, c3_b1, he_bf);
  msg_mfma<90, 45, 2, 2, 256><<<NE / 128, 256, 0, stream>>>(he_bf, h2, src, dst, wp3, agg);
  node_kernel<90, 45><<<(NN * 45 + 255) / 256, 256, 0, stream>>>(agg, h2, c3_root, c3_bias, h3);

  pool_mlp_kernel<<<NG, 128, 0, stream>>>(h3, batch, fc1_w, fc1_b, out_w, out_b, (float*)d_out);
}

// Round 11
// 601.289 us; speedup vs baseline: 2.2394x; 1.0154x over previous
//
#include <hip/hip_runtime.h>

#define NN 16000   // nodes
#define NE 64000   // edges
#define HD 90      // hidden
#define NG 512     // graphs

typedef float f32x4 __attribute__((ext_vector_type(4)));
typedef float f32x16 __attribute__((ext_vector_type(16)));
typedef short s16x8 __attribute__((ext_vector_type(8)));

// round-half-up f32 -> bf16
__device__ __forceinline__ unsigned short rhu1(float f) {
  return (unsigned short)((__builtin_bit_cast(unsigned int, f) + 0x8000u) >> 16);
}
// pack two f32 -> bf16x2 (lo in low half), RHU rounding
__device__ __forceinline__ unsigned int rhu_pack(float lo, float hi) {
  unsigned int ul = __builtin_bit_cast(unsigned int, lo) + 0x8000u;
  unsigned int uh = __builtin_bit_cast(unsigned int, hi) + 0x8000u;
  return __builtin_amdgcn_perm(uh, ul, 0x07060302u);
}
__device__ __forceinline__ float bfhi(unsigned int u) {
  return __builtin_bit_cast(float, u & 0xFFFF0000u);
}
__device__ __forceinline__ float bflo(unsigned int u) {
  return __builtin_bit_cast(float, u << 16);
}

// h0 = concat(x, pos) : [NN, 16]
__global__ void concat_kernel(const float* __restrict__ x, const float* __restrict__ pos,
                              float* __restrict__ h0) {
  int idx = blockIdx.x * 256 + threadIdx.x;
  if (idx >= NN * 16) return;
  int n = idx >> 4, c = idx & 15;
  h0[idx] = (c < 13) ? x[n * 13 + c] : pos[n * 3 + (c - 13)];
}

// he_bf[e][k] : [NE, 96] bf16. k<90: relu(edge MLP); k==90: 1.0 (bias row); k>90: 0
__global__ void edge_mlp_bf(const float* __restrict__ ea, const float* __restrict__ w1,
                            const float* __restrict__ b1, unsigned short* __restrict__ he) {
  int idx = blockIdx.x * 256 + threadIdx.x;
  if (idx >= NE * 96) return;
  int e = idx / 96, k = idx - e * 96;
  unsigned short v;
  if (k < 90) {
    const float* a = ea + e * 8;
    float acc = b1[k];
#pragma unroll
    for (int j = 0; j < 8; j++) acc = fmaf(a[j], w1[j * HD + k], acc);
    v = rhu1(fmaxf(acc, 0.f));
  } else {
    v = (k == 90) ? (unsigned short)0x3F80 : (unsigned short)0;  // bf16(1.0) / 0
  }
  he[idx] = v;
}

// W' prep, 32x32x16 B-fragment order: shorts as [i][ot(NOT)][c(6)][lane(64)][j(8)]
//   o = ot*32 + (lane&31), hk = c*16 + (lane>>5)*8 + j
//   hk<90 -> w2[hk][i*OC+o]; hk==90 -> b2[i*OC+o]; else 0.  One block per i.
template <int OC, int NOT>
__global__ void wprep_frag32(const float* __restrict__ w2, const float* __restrict__ b2,
                             unsigned short* __restrict__ wout, int inc_oc) {
  const int i = blockIdx.x;
  unsigned int* wo = (unsigned int*)(wout + (size_t)i * NOT * 6 * 512);
  for (int u = threadIdx.x; u < NOT * 6 * 256; u += 256) {
    int f = u >> 8, r = u & 255;
    int ot = f / 6;
    int c = f - 6 * ot;
    int lane = r >> 2, uu = r & 3;
    int o = ot * 32 + (lane & 31);
    int hk = c * 16 + ((lane >> 5) << 3) + 2 * uu;
    float v0 = 0.f, v1 = 0.f;
    if (o < OC) {
      if (hk < 90) v0 = w2[hk * inc_oc + i * OC + o];
      else if (hk == 90) v0 = b2[i * OC + o];
      int hk1 = hk + 1;
      if (hk1 < 90) v1 = w2[hk1 * inc_oc + i * OC + o];
      else if (hk1 == 90) v1 = b2[i * OC + o];
    }
    wo[u] = rhu_pack(v0, v1);
  }
}

// ---- msg kernel pipeline macros (plain arrays, constant post-unroll indices) ----
#define LOADB(II, B)                                                           \
  do {                                                                         \
    const unsigned short* wg_ = wl + ((size_t)((II) * NOT + wn) * 6 + kh3) * 512; \
    B[0] = *(const s16x8*)(wg_);                                               \
    B[1] = *(const s16x8*)(wg_ + 512);                                         \
    B[2] = *(const s16x8*)(wg_ + 1024);                                        \
  } while (0)

#define BODY(II, B)                                                            \
  do {                                                                         \
    _Pragma("unroll")                                                          \
    for (int mt = 0; mt < 2; mt++) {                                           \
      const int zbase = (II) * 64 + mt * 32 + h * 16;                          \
      const uint4 za = *(const uint4*)&zb[zbase];                              \
      const uint4 zc = *(const uint4*)&zb[zbase + 8];                          \
      f32x16 t = __builtin_amdgcn_mfma_f32_32x32x16_bf16(af[mt][0], B[0], (f32x16)0.f, 0, 0, 0); \
      t = __builtin_amdgcn_mfma_f32_32x32x16_bf16(af[mt][1], B[1], t, 0, 0, 0);\
      t = __builtin_amdgcn_mfma_f32_32x32x16_bf16(af[mt][2], B[2], t, 0, 0, 0);\
      f32x16 zv;                                                               \
      zv[0] = bflo(za.x);  zv[1] = bfhi(za.x);  zv[2] = bflo(za.y);  zv[3] = bfhi(za.y); \
      zv[4] = bflo(za.z);  zv[5] = bfhi(za.z);  zv[6] = bflo(za.w);  zv[7] = bfhi(za.w); \
      zv[8] = bflo(zc.x);  zv[9] = bfhi(zc.x);  zv[10] = bflo(zc.y); zv[11] = bfhi(zc.y); \
      zv[12] = bflo(zc.z); zv[13] = bfhi(zc.z); zv[14] = bflo(zc.w); zv[15] = bfhi(zc.w); \
      acc[mt] += zv * t;                                                       \
    }                                                                          \
  } while (0)

// Fused message GEMM + scatter, i-outer, barrier-free K-loop, 32x32x16 core,
// K-SPLIT wave specialization:
//   wave (wn, kh): tmp_half = he[:, kh*48:(kh+1)*48] @ W'[i]-half  (3 chained MFMAs)
//   acc += z[e][i] * tmp_half; halves merged once per block via LDS, then atomics.
// af 24 VGPR (half-K) frees room for DOUBLE-buffered B (b0/b1, 12 each) ->
// ~95 arch VGPRs, well under the ~130 allocator cliff (R5/R9 lessons).
// Block: 64 edges (2 m-tiles/wave), waves = NOT n-groups x 2 K-halves.
template <int ILIM, int OC, int NOT, int BLK>
__global__ __launch_bounds__(BLK, 3)
void msg_mfma(const unsigned short* __restrict__ he,
              const float* __restrict__ nin,
              const int* __restrict__ src, const int* __restrict__ dst,
              const unsigned short* __restrict__ wp,
              float* __restrict__ agg) {
  __shared__ unsigned short zb[ILIM * 64];    // [i][mt][h][qq*4+rr] bf16
  __shared__ float mrg[NOT * 64 * 32];        // kh=1 partials for merge
  __shared__ int dst_s[64];
  const int tid = threadIdx.x;
  const int e0 = blockIdx.x * 64;
  const int wid = tid >> 6, l = tid & 63, ln32 = l & 31, h = l >> 5;
  const int kh = wid & 1, wn = wid >> 1;
  const int kh3 = kh * 3;

  if (tid < 64) dst_s[tid] = dst[e0 + tid];

  // stage z (bf16), permuted: perm(e) = (e>>5)*32 + ((e>>2)&1)*16 + ((e>>3)&3)*4 + (e&3)
  {
    const int e = tid & 63, jj = tid >> 6;           // jj in [0, NOT*2)
    const int pe = ((e >> 5) << 5) + (((e >> 2) & 1) << 4) + (((e >> 3) & 3) << 2) + (e & 3);
    const float* zr = nin + (size_t)src[e0 + e] * ILIM;
    for (int p = jj; p < ILIM / 2; p += NOT * 2) {
      const float2 v = *(const float2*)(zr + 2 * p);
      zb[(2 * p) * 64 + pe] = rhu1(v.x);
      zb[(2 * p + 1) * 64 + pe] = rhu1(v.y);
    }
  }

  // A-fragments: he rows, this wave's K-half (32x32x16 A: m=lane&31, k=c*16+h*8+j)
  s16x8 af[2][3];
#pragma unroll
  for (int mt = 0; mt < 2; mt++) {
    const unsigned short* hr = he + (size_t)(e0 + mt * 32 + ln32) * 96 + kh * 48 + h * 8;
#pragma unroll
    for (int c = 0; c < 3; c++) af[mt][c] = *(const s16x8*)(hr + c * 16);
  }

  const unsigned short* wl = wp + l * 8;
  s16x8 b0[3], b1[3];
  LOADB(0, b0);

  __syncthreads();   // zb/dst_s ready; no barriers in the K-loop

  f32x16 acc[2];
  acc[0] = (f32x16)0.f;
  acc[1] = (f32x16)0.f;

#pragma clang loop unroll(disable)
  for (int i = 0; i < ILIM; i += 2) {
    if (i + 1 < ILIM) LOADB(i + 1, b1);   // full-iteration prefetch depth
    BODY(i, b0);
    if (i + 1 < ILIM) {
      if (i + 2 < ILIM) LOADB(i + 2, b0);
      BODY(i + 1, b1);
    }
  }

  // merge K-halves via LDS, then scatter (atomic count unchanged vs prior rounds)
  if (kh) {
    float* mr = &mrg[wn * 2048];
#pragma unroll
    for (int mt = 0; mt < 2; mt++)
#pragma unroll
      for (int r = 0; r < 16; r++) {
        int row = (r & 3) + 8 * (r >> 2) + 4 * h;
        mr[(mt * 32 + row) * 32 + ln32] = acc[mt][r];
      }
  }
  __syncthreads();
  if (!kh) {
    const int o = wn * 32 + ln32;
    if (o < OC) {
      const float* mr = &mrg[wn * 2048];
#pragma unroll
      for (int mt = 0; mt < 2; mt++)
#pragma unroll
        for (int r = 0; r < 16; r++) {
          int row = (r & 3) + 8 * (r >> 2) + 4 * h;
          int el = mt * 32 + row;
          atomicAdd(agg + (size_t)dst_s[el] * OC + o, acc[mt][r] + mr[el * 32 + ln32]);
        }
    }
  }
}

// out[n][o] = relu(agg[n][o] + sum_i nin[n][i]*root[i][o] + bias[o])   (fp32 exact)
template <int IN_C, int OC>
__global__ void node_kernel(const float* __restrict__ agg, const float* __restrict__ nin,
                            const float* __restrict__ root, const float* __restrict__ bias,
                            float* __restrict__ out) {
  int idx = blockIdx.x * 256 + threadIdx.x;
  if (idx >= NN * OC) return;
  int n = idx / OC, o = idx - n * OC;
  float acc = agg[idx] + bias[o];
  const float* inp = nin + (size_t)n * IN_C;
#pragma unroll 6
  for (int i = 0; i < IN_C; i++) acc = fmaf(inp[i], root[i * OC + o], acc);
  out[idx] = fmaxf(acc, 0.f);
}

// per-graph: pool (batch sorted -> binary search) + fc1 + out
__global__ void pool_mlp_kernel(const float* __restrict__ h3, const int* __restrict__ batch,
                                const float* __restrict__ fc1_w, const float* __restrict__ fc1_b,
                                const float* __restrict__ out_w, const float* __restrict__ out_b,
                                float* __restrict__ out) {
  const int b = blockIdx.x;
  const int tid = threadIdx.x;
  __shared__ float g[45];
  __shared__ float go[90];
  __shared__ int rng[2];
  if (tid < 2) {
    int target = b + tid;
    int lo = 0, hi = NN;
    while (lo < hi) { int mid = (lo + hi) >> 1; if (batch[mid] < target) lo = mid + 1; else hi = mid; }
    rng[tid] = lo;
  }
  __syncthreads();
  const int s = rng[0], e = rng[1];
  if (tid < 45) {
    float acc = 0.f;
    for (int n = s; n < e; n++) acc += h3[n * 45 + tid];
    g[tid] = acc;
  }
  __syncthreads();
  if (tid < 90) {
    float acc = fc1_b[tid];
#pragma unroll 5
    for (int i = 0; i < 45; i++) acc = fmaf(g[i], fc1_w[i * 90 + tid], acc);
    go[tid] = fmaxf(acc, 0.f) * out_w[tid];
  }
  __syncthreads();
  if (tid == 0) {
    float acc = out_b[0];
    for (int i = 0; i < 90; i++) acc += go[i];
    out[b] = acc;
  }
}

extern "C" void kernel_launch(void* const* d_in, const int* in_sizes, int n_in,
                              void* d_out, int out_size, void* d_ws, size_t ws_size,
                              hipStream_t stream) {
  const float* x       = (const float*)d_in[0];
  const float* pos     = (const float*)d_in[1];
  const float* ea      = (const float*)d_in[2];
  const int*   eidx    = (const int*)d_in[3];
  const int*   batch   = (const int*)d_in[4];
  const float* c1_w1   = (const float*)d_in[5];
  const float* c1_b1   = (const float*)d_in[6];
  const float* c1_w2   = (const float*)d_in[7];
  const float* c1_b2   = (const float*)d_in[8];
  const float* c1_root = (const float*)d_in[9];
  const float* c1_bias = (const float*)d_in[10];
  const float* c2_w1   = (const float*)d_in[11];
  const float* c2_b1   = (const float*)d_in[12];
  const float* c2_w2   = (const float*)d_in[13];
  const float* c2_b2   = (const float*)d_in[14];
  const float* c2_root = (const float*)d_in[15];
  const float* c2_bias = (const float*)d_in[16];
  const float* c3_w1   = (const float*)d_in[17];
  const float* c3_b1   = (const float*)d_in[18];
  const float* c3_w2   = (const float*)d_in[19];
  const float* c3_b2   = (const float*)d_in[20];
  const float* c3_root = (const float*)d_in[21];
  const float* c3_bias = (const float*)d_in[22];
  const float* fc1_w   = (const float*)d_in[23];
  const float* fc1_b   = (const float*)d_in[24];
  const float* out_w   = (const float*)d_in[25];
  const float* out_b   = (const float*)d_in[26];
  const int* src = eidx;
  const int* dst = eidx + NE;

  // workspace carve
  float* ws  = (float*)d_ws;
  float* h0  = ws;                       // NN*16
  float* h1  = h0 + NN * 16;             // NN*90
  float* h2  = h1 + NN * 90;             // NN*90
  float* h3  = h2 + NN * 90;             // NN*45
  float* agg = h3 + NN * 45;             // NN*90
  unsigned short* he_bf = (unsigned short*)(agg + NN * 90);   // NE*96
  unsigned short* wp1 = he_bf + (size_t)NE * 96;              // 16*3*6*512
  unsigned short* wp2 = wp1 + (size_t)16 * 3 * 6 * 512;       // 90*3*6*512
  unsigned short* wp3 = wp2 + (size_t)90 * 3 * 6 * 512;       // 90*2*6*512

  concat_kernel<<<(NN * 16) / 256, 256, 0, stream>>>(x, pos, h0);

  wprep_frag32<90, 3><<<16, 256, 0, stream>>>(c1_w2, c1_b2, wp1, 16 * 90);
  wprep_frag32<90, 3><<<90, 256, 0, stream>>>(c2_w2, c2_b2, wp2, 90 * 90);
  wprep_frag32<45, 2><<<90, 256, 0, stream>>>(c3_w2, c3_b2, wp3, 90 * 45);

  // conv1: 16 -> 90   (64 edges/block; 6 waves = 3 n-groups x 2 K-halves)
  hipMemsetAsync(agg, 0, (size_t)NN * 90 * sizeof(float), stream);
  edge_mlp_bf<<<(NE * 96) / 256, 256, 0, stream>>>(ea, c1_w1, c1_b1, he_bf);
  msg_mfma<16, 90, 3, 384><<<NE / 64, 384, 0, stream>>>(he_bf, h0, src, dst, wp1, agg);
  node_kernel<16, 90><<<(NN * 90) / 256, 256, 0, stream>>>(agg, h0, c1_root, c1_bias, h1);

  // conv2: 90 -> 90
  hipMemsetAsync(agg, 0, (size_t)NN * 90 * sizeof(float), stream);
  edge_mlp_bf<<<(NE * 96) / 256, 256, 0, stream>>>(ea, c2_w1, c2_b1, he_bf);
  msg_mfma<90, 90, 3, 384><<<NE / 64, 384, 0, stream>>>(he_bf, h1, src, dst, wp2, agg);
  node_kernel<90, 90><<<(NN * 90) / 256, 256, 0, stream>>>(agg, h1, c2_root, c2_bias, h2);

  // conv3: 90 -> 45   (64 edges/block; 4 waves = 2 n-groups x 2 K-halves)
  hipMemsetAsync(agg, 0, (size_t)NN * 45 * sizeof(float), stream);
  edge_mlp_bf<<<(NE * 96) / 256, 256, 0, stream>>>(ea, c3_w1, c3_b1, he_bf);
  msg_mfma<90, 45, 2, 256><<<NE / 64, 256, 0, stream>>>(he_bf, h2, src, dst, wp3, agg);
  node_kernel<90, 45><<<(NN * 45 + 255) / 256, 256, 0, stream>>>(agg, h2, c3_root, c3_bias, h3);

  pool_mlp_kernel<<<NG, 128, 0, stream>>>(h3, batch, fc1_w, fc1_b, out_w, out_b, (float*)d_out);
}